// Round 2
// baseline (214.847 us; speedup 1.0000x reference)
//
#include <hip/hip_runtime.h>
#include <hip/hip_bf16.h>
#include <cstdint>
#include <cstddef>

// Problem dims (fixed by the reference)
#define NEXP   8
#define BATCH  8
#define NTOK   2048
#define DDIM   512
#define DFFDIM 2048
#define DCOND  512

typedef float  f32x4  __attribute__((ext_vector_type(4)));
typedef __bf16 bf16x8 __attribute__((ext_vector_type(8)));

using as1_cvoid = __attribute__((address_space(1))) const void;
using as3_void  = __attribute__((address_space(3))) void;

__device__ __forceinline__ void async_copy16(const void* g, void* l) {
  __builtin_amdgcn_global_load_lds((as1_cvoid*)g, (as3_void*)l, 16, 0, 0);
}

__device__ __forceinline__ unsigned short f2bf_bits(float f) {
  __hip_bfloat16 h = __float2bfloat16(f);
  return *reinterpret_cast<unsigned short*>(&h);
}

// ---------------------------------------------------------------------------
// 1) scale/shift = cond[b] @ W_cond[route[b]] + b_cond[route[b]]   -> ss[B][1024]
// ---------------------------------------------------------------------------
__global__ void mod_kernel(const float* __restrict__ cond,
                           const int* __restrict__ route,
                           const float* __restrict__ W_cond,
                           const float* __restrict__ b_cond,
                           float* __restrict__ ss) {
  const int b = blockIdx.y;
  const int m = route[b];
  const int j = blockIdx.x * blockDim.x + threadIdx.x;   // 0..2D-1
  const float* wc = W_cond + (size_t)m * DCOND * (2 * DDIM);
  const float* cb = cond + (size_t)b * DCOND;
  float acc = 0.f;
#pragma unroll 4
  for (int c = 0; c < DCOND; ++c)
    acc += cb[c] * wc[(size_t)c * (2 * DDIM) + j];
  ss[(size_t)b * (2 * DDIM) + j] = acc + b_cond[(size_t)m * (2 * DDIM) + j];
}

// ---------------------------------------------------------------------------
// 2) x_mod = bf16( x * (1+scale) + shift )   [B][N][D] bf16
// ---------------------------------------------------------------------------
__global__ void film_kernel(const float* __restrict__ x,
                            const float* __restrict__ ss,
                            __hip_bfloat16* __restrict__ xmod) {
  const size_t idx = (size_t)blockIdx.x * blockDim.x + threadIdx.x; // float4 group
  const int d4 = (int)(idx & (DDIM / 4 - 1));          // 0..127
  const int b  = (int)(idx >> 18);                      // / (N * D/4) = 2^18
  const float4 xv = reinterpret_cast<const float4*>(x)[idx];
  const float4 sc = reinterpret_cast<const float4*>(ss + (size_t)b * 1024)[d4];
  const float4 sh = reinterpret_cast<const float4*>(ss + (size_t)b * 1024 + DDIM)[d4];
  float r0 = xv.x * (1.f + sc.x) + sh.x;
  float r1 = xv.y * (1.f + sc.y) + sh.y;
  float r2 = xv.z * (1.f + sc.z) + sh.z;
  float r3 = xv.w * (1.f + sc.w) + sh.w;
  ushort4 ov;
  ov.x = f2bf_bits(r0); ov.y = f2bf_bits(r1);
  ov.z = f2bf_bits(r2); ov.w = f2bf_bits(r3);
  reinterpret_cast<ushort4*>(xmod)[idx] = ov;
}

// ---------------------------------------------------------------------------
// 3) transpose + f32->bf16:  in [M][L][R] f32  ->  out [M][R][L] bf16
// ---------------------------------------------------------------------------
__global__ void transpose_cvt(const float* __restrict__ in,
                              __hip_bfloat16* __restrict__ outp,
                              int L, int R) {
  __shared__ float tile[32][33];
  const int mi = blockIdx.z;
  const float* inm = in + (size_t)mi * L * R;
  __hip_bfloat16* outm = outp + (size_t)mi * L * R;
  const int r0 = blockIdx.x * 32, l0 = blockIdx.y * 32;
  const int tx = threadIdx.x, ty = threadIdx.y;
#pragma unroll
  for (int i = 0; i < 32; i += 8)
    tile[ty + i][tx] = inm[(size_t)(l0 + ty + i) * R + r0 + tx];
  __syncthreads();
#pragma unroll
  for (int i = 0; i < 32; i += 8)
    outm[(size_t)(r0 + ty + i) * L + l0 + tx] = __float2bfloat16(tile[tx][ty + i]);
}

// ---------------------------------------------------------------------------
// 4) GEMM (m97 structure): A [b][Mdim][Kdim] bf16 row-major,
//    Bt [m][Ndim][Kdim] bf16 row-major (B transposed), bias [m][Ndim] f32.
//    EPI=0: out = bf16(gelu_tanh(acc+bias)) -> h;  EPI=1: out = f32(acc+bias)
//    Tile 128x128, BK=64, 256 threads (4 waves, 2x2), 16x16x32 bf16 MFMA.
// ---------------------------------------------------------------------------
template <int EPI>
__global__ __launch_bounds__(256) void gemm_bt(
    const __hip_bfloat16* __restrict__ Abase,
    const __hip_bfloat16* __restrict__ Btbase,
    const float* __restrict__ biasbase,
    void* __restrict__ outbase,
    const int* __restrict__ route,
    int Mdim, int Ndim, int Kdim) {
  const int b = blockIdx.z;
  const int m = route[b];
  const __hip_bfloat16* A  = Abase  + (size_t)b * Mdim * Kdim;
  const __hip_bfloat16* Bt = Btbase + (size_t)m * Ndim * Kdim;
  const float* bias = biasbase + (size_t)m * Ndim;
  const int r0 = blockIdx.x * 128;
  const int n0 = blockIdx.y * 128;

  __shared__ alignas(16) __hip_bfloat16 As[128 * 64];
  __shared__ alignas(16) __hip_bfloat16 Bs[128 * 64];

  const int t = threadIdx.x;
  const int w = t >> 6;         // wave 0..3
  const int l = t & 63;         // lane
  const int wr = w >> 1, wc = w & 1;

  f32x4 acc[4][4] = {};

  const int lrow = l >> 3;      // 0..7 (row within 8-row staging chunk)
  const int lcol = (l & 7) * 8; // 0..56 (k offset within chunk)

  for (int k0 = 0; k0 < Kdim; k0 += 64) {
    // ---- stage A-tile and Bt-tile into LDS (global_load_lds width 16) ----
#pragma unroll
    for (int i = 0; i < 4; ++i) {
      const int c = w * 4 + i;  // chunk 0..15, covers rows [c*8, c*8+8)
      const __hip_bfloat16* ga = A  + (size_t)(r0 + c * 8 + lrow) * Kdim + k0 + lcol;
      async_copy16(ga, &As[c * 512]);
      const __hip_bfloat16* gb = Bt + (size_t)(n0 + c * 8 + lrow) * Kdim + k0 + lcol;
      async_copy16(gb, &Bs[c * 512]);
    }
    __syncthreads();

    // ---- compute: 2 k32 steps, 16 MFMA each ----
#pragma unroll
    for (int kk = 0; kk < 2; ++kk) {
      bf16x8 a[4], bb[4];
      const int koff = kk * 32 + (l >> 4) * 8;
#pragma unroll
      for (int mi = 0; mi < 4; ++mi)
        a[mi] = *reinterpret_cast<const bf16x8*>(
            &As[(wr * 64 + mi * 16 + (l & 15)) * 64 + koff]);
#pragma unroll
      for (int ni = 0; ni < 4; ++ni)
        bb[ni] = *reinterpret_cast<const bf16x8*>(
            &Bs[(wc * 64 + ni * 16 + (l & 15)) * 64 + koff]);
#pragma unroll
      for (int mi = 0; mi < 4; ++mi)
#pragma unroll
        for (int ni = 0; ni < 4; ++ni)
          acc[mi][ni] = __builtin_amdgcn_mfma_f32_16x16x32_bf16(
              a[mi], bb[ni], acc[mi][ni], 0, 0, 0);
    }
    __syncthreads();
  }

  // ---- epilogue: C/D layout col=lane&15, row=(lane>>4)*4+reg ----
  if (EPI == 0) {
    __hip_bfloat16* out = (__hip_bfloat16*)outbase + (size_t)b * Mdim * Ndim;
#pragma unroll
    for (int mi = 0; mi < 4; ++mi) {
      const int row = r0 + wr * 64 + mi * 16 + (l >> 4) * 4;
#pragma unroll
      for (int ni = 0; ni < 4; ++ni) {
        const int col = n0 + wc * 64 + ni * 16 + (l & 15);
        const float bv = bias[col];
#pragma unroll
        for (int j = 0; j < 4; ++j) {
          float v = acc[mi][ni][j] + bv;
          float u = v + 0.044715f * v * v * v;
          float g = 0.5f * v * (1.0f + tanhf(0.7978845608028654f * u));
          out[(size_t)(row + j) * Ndim + col] = __float2bfloat16(g);
        }
      }
    }
  } else {
    float* out = (float*)outbase + (size_t)b * Mdim * Ndim;
#pragma unroll
    for (int mi = 0; mi < 4; ++mi) {
      const int row = r0 + wr * 64 + mi * 16 + (l >> 4) * 4;
#pragma unroll
      for (int ni = 0; ni < 4; ++ni) {
        const int col = n0 + wc * 64 + ni * 16 + (l & 15);
        const float bv = bias[col];
#pragma unroll
        for (int j = 0; j < 4; ++j)
          out[(size_t)(row + j) * Ndim + col] = acc[mi][ni][j] + bv;
      }
    }
  }
}

// ---------------------------------------------------------------------------
extern "C" void kernel_launch(void* const* d_in, const int* in_sizes, int n_in,
                              void* d_out, int out_size, void* d_ws, size_t ws_size,
                              hipStream_t stream) {
  const float* x      = (const float*)d_in[0];
  const float* cond   = (const float*)d_in[1];
  const int*   route  = (const int*)d_in[2];    // harness passes integers as int32
  const float* W_cond = (const float*)d_in[3];
  const float* b_cond = (const float*)d_in[4];
  const float* W1     = (const float*)d_in[5];
  const float* b1     = (const float*)d_in[6];
  const float* W2     = (const float*)d_in[7];
  const float* b2     = (const float*)d_in[8];
  float* out = (float*)d_out;

  // workspace layout (bytes)
  const size_t SS_OFF   = 0;                                  // [B][1024] f32  = 32 KB
  const size_t XMOD_OFF = 32768;                              // [B][N][D] bf16 = 16 MB
  const size_t W1T_OFF  = XMOD_OFF + (size_t)BATCH * NTOK * DDIM * 2;       // [M][DFF][D] bf16
  const size_t W2T_OFF  = W1T_OFF + (size_t)NEXP * DDIM * DFFDIM * 2;       // [M][D][DFF] bf16
  const size_t H_OFF    = W2T_OFF + (size_t)NEXP * DFFDIM * DDIM * 2;       // [B][N][DFF] bf16
  const size_t NEED     = H_OFF + (size_t)BATCH * NTOK * DFFDIM * 2;
  if (ws_size < NEED) return;  // insufficient scratch -> visible failure

  char* ws = (char*)d_ws;
  float* ss            = (float*)(ws + SS_OFF);
  __hip_bfloat16* xmod = (__hip_bfloat16*)(ws + XMOD_OFF);
  __hip_bfloat16* w1t  = (__hip_bfloat16*)(ws + W1T_OFF);
  __hip_bfloat16* w2t  = (__hip_bfloat16*)(ws + W2T_OFF);
  __hip_bfloat16* h    = (__hip_bfloat16*)(ws + H_OFF);

  // 1) cond modulation
  mod_kernel<<<dim3(2 * DDIM / 256, BATCH), 256, 0, stream>>>(cond, route, W_cond, b_cond, ss);

  // 2) FiLM -> bf16
  {
    const size_t groups = (size_t)BATCH * NTOK * DDIM / 4;  // 2,097,152
    film_kernel<<<(unsigned)(groups / 256), 256, 0, stream>>>(x, ss, xmod);
  }

  // 3) weight transpose+convert:  W1 [M][D][DFF] -> w1t [M][DFF][D]
  transpose_cvt<<<dim3(DFFDIM / 32, DDIM / 32, NEXP), dim3(32, 8), 0, stream>>>(W1, w1t, DDIM, DFFDIM);
  //                      W2 [M][DFF][D] -> w2t [M][D][DFF]
  transpose_cvt<<<dim3(DDIM / 32, DFFDIM / 32, NEXP), dim3(32, 8), 0, stream>>>(W2, w2t, DFFDIM, DDIM);

  // 4) GEMM1: h = gelu(xmod @ W1 + b1)   [per b, expert route[b]]
  gemm_bt<0><<<dim3(NTOK / 128, DFFDIM / 128, BATCH), 256, 0, stream>>>(
      xmod, w1t, b1, h, route, NTOK, DFFDIM, DDIM);

  // 5) GEMM2: out = h @ W2 + b2
  gemm_bt<1><<<dim3(NTOK / 128, DDIM / 128, BATCH), 256, 0, stream>>>(
      h, w2t, b2, out, route, NTOK, DDIM, DFFDIM);
}

// Round 3
// 187.361 us; speedup vs baseline: 1.1467x; 1.1467x over previous
//
#include <hip/hip_runtime.h>
#include <hip/hip_bf16.h>
#include <cstdint>
#include <cstddef>

// Problem dims (fixed by the reference)
#define NEXP   8
#define BATCH  8
#define NTOK   2048
#define DDIM   512
#define DFFDIM 2048
#define DCOND  512

typedef float  f32x4  __attribute__((ext_vector_type(4)));
typedef __bf16 bf16x8 __attribute__((ext_vector_type(8)));

using as1_cvoid = __attribute__((address_space(1))) const void;
using as3_void  = __attribute__((address_space(3))) void;

__device__ __forceinline__ void async_copy16(const void* g, void* l) {
  __builtin_amdgcn_global_load_lds((as1_cvoid*)g, (as3_void*)l, 16, 0, 0);
}

__device__ __forceinline__ unsigned short f2bf_bits(float f) {
  __hip_bfloat16 h = __float2bfloat16(f);
  return *reinterpret_cast<unsigned short*>(&h);
}

// fast tanh-approx gelu: 0.5v(1+tanh(z)) == v * sigmoid(2z)
__device__ __forceinline__ float gelu_fast(float v) {
  float y = v * fmaf(0.0713548162726f, v * v, 1.5957691216057f); // 2*0.79788456*(1+0.044715 v^2)
  float e = exp2f(-1.44269504089f * y);                          // v_exp_f32
  return v * __builtin_amdgcn_rcpf(1.0f + e);                    // v_rcp_f32
}

// ---------------------------------------------------------------------------
// 1) scale/shift = cond[b] @ W_cond[route[b]] + b_cond[route[b]]   -> ss[B][1024]
// ---------------------------------------------------------------------------
__global__ void mod_kernel(const float* __restrict__ cond,
                           const int* __restrict__ route,
                           const float* __restrict__ W_cond,
                           const float* __restrict__ b_cond,
                           float* __restrict__ ss) {
  const int b = blockIdx.y;
  const int m = route[b];
  const int j = blockIdx.x * blockDim.x + threadIdx.x;   // 0..2D-1
  const float* wc = W_cond + (size_t)m * DCOND * (2 * DDIM);
  const float* cb = cond + (size_t)b * DCOND;
  float acc = 0.f;
#pragma unroll 4
  for (int c = 0; c < DCOND; ++c)
    acc += cb[c] * wc[(size_t)c * (2 * DDIM) + j];
  ss[(size_t)b * (2 * DDIM) + j] = acc + b_cond[(size_t)m * (2 * DDIM) + j];
}

// ---------------------------------------------------------------------------
// 2) x_mod = bf16( x * (1+scale) + shift )   [B][N][D] bf16
// ---------------------------------------------------------------------------
__global__ void film_kernel(const float* __restrict__ x,
                            const float* __restrict__ ss,
                            __hip_bfloat16* __restrict__ xmod) {
  const size_t idx = (size_t)blockIdx.x * blockDim.x + threadIdx.x; // float4 group
  const int d4 = (int)(idx & (DDIM / 4 - 1));          // 0..127
  const int b  = (int)(idx >> 18);                      // / (N * D/4) = 2^18
  const float4 xv = reinterpret_cast<const float4*>(x)[idx];
  const float4 sc = reinterpret_cast<const float4*>(ss + (size_t)b * 1024)[d4];
  const float4 sh = reinterpret_cast<const float4*>(ss + (size_t)b * 1024 + DDIM)[d4];
  float r0 = xv.x * (1.f + sc.x) + sh.x;
  float r1 = xv.y * (1.f + sc.y) + sh.y;
  float r2 = xv.z * (1.f + sc.z) + sh.z;
  float r3 = xv.w * (1.f + sc.w) + sh.w;
  ushort4 ov;
  ov.x = f2bf_bits(r0); ov.y = f2bf_bits(r1);
  ov.z = f2bf_bits(r2); ov.w = f2bf_bits(r3);
  reinterpret_cast<ushort4*>(xmod)[idx] = ov;
}

// ---------------------------------------------------------------------------
// 3) transpose + f32->bf16:  in [M][L][R] f32  ->  out [M][R][L] bf16
//    Skips experts not present in route.
// ---------------------------------------------------------------------------
__global__ void transpose_cvt(const float* __restrict__ in,
                              __hip_bfloat16* __restrict__ outp,
                              int L, int R,
                              const int* __restrict__ route) {
  const int mi = blockIdx.z;
  bool used = false;
#pragma unroll
  for (int b = 0; b < BATCH; ++b) used |= (route[b] == mi);
  if (!used) return;   // uniform across block

  __shared__ float tile[32][33];
  const float* inm = in + (size_t)mi * L * R;
  __hip_bfloat16* outm = outp + (size_t)mi * L * R;
  const int r0 = blockIdx.x * 32, l0 = blockIdx.y * 32;
  const int tx = threadIdx.x, ty = threadIdx.y;
#pragma unroll
  for (int i = 0; i < 32; i += 8)
    tile[ty + i][tx] = inm[(size_t)(l0 + ty + i) * R + r0 + tx];
  __syncthreads();
#pragma unroll
  for (int i = 0; i < 32; i += 8)
    outm[(size_t)(r0 + ty + i) * L + l0 + tx] = __float2bfloat16(tile[tx][ty + i]);
}

// ---------------------------------------------------------------------------
// 4) GEMM, double-buffered (T3-minimum 2-phase recipe):
//    A [b][Mdim][Kdim] bf16 row-major, Bt [m][Ndim][Kdim] bf16 (B transposed),
//    bias [m][Ndim] f32.  Tile 128x128, BK=64, 256 threads (4 waves, 2x2).
//    EPI=0: out = bf16(gelu(acc+bias));  EPI=1: out = f32(acc+bias)
//    1D grid with z-major XCD swizzle: XCD k owns batch b=k.
// ---------------------------------------------------------------------------
template <int EPI>
__global__ __launch_bounds__(256) void gemm_db(
    const __hip_bfloat16* __restrict__ Abase,
    const __hip_bfloat16* __restrict__ Btbase,
    const float* __restrict__ biasbase,
    void* __restrict__ outbase,
    const int* __restrict__ route,
    int Mdim, int Ndim, int Kdim, int tilesX, int tilesY) {
  // --- XCD-aware bijective swizzle (grid size divisible by 8) ---
  const int n = gridDim.x;
  const int bid = blockIdx.x;
  const int wg = (bid & 7) * (n >> 3) + (bid >> 3);
  const int bx = wg % tilesX;
  const int by = (wg / tilesX) % tilesY;
  const int b  = wg / (tilesX * tilesY);

  const int m = route[b];
  const __hip_bfloat16* A  = Abase  + (size_t)b * Mdim * Kdim;
  const __hip_bfloat16* Bt = Btbase + (size_t)m * Ndim * Kdim;
  const float* bias = biasbase + (size_t)m * Ndim;
  const int r0 = bx * 128;
  const int n0 = by * 128;

  __shared__ alignas(16) __hip_bfloat16 As[2][128 * 64];
  __shared__ alignas(16) __hip_bfloat16 Bs[2][128 * 64];

  const int t = threadIdx.x;
  const int w = t >> 6;         // wave 0..3
  const int l = t & 63;         // lane
  const int wr = w >> 1, wc = w & 1;

  f32x4 acc[4][4] = {};

  const int lrow = l >> 3;      // 0..7 (row within 8-row staging chunk)
  const int lcol = (l & 7) * 8; // 0..56 (k offset within chunk)

  const int nt = Kdim >> 6;     // K-tiles of 64

  // stage K-tile (k0) into buffer buf
#define STAGE(buf, k0)                                                        \
  {                                                                           \
    _Pragma("unroll")                                                         \
    for (int i = 0; i < 4; ++i) {                                             \
      const int c = w * 4 + i;                                                \
      async_copy16(A  + (size_t)(r0 + c * 8 + lrow) * Kdim + (k0) + lcol,     \
                   &As[buf][c * 512]);                                        \
      async_copy16(Bt + (size_t)(n0 + c * 8 + lrow) * Kdim + (k0) + lcol,     \
                   &Bs[buf][c * 512]);                                        \
    }                                                                         \
  }

  // prologue: stage tile 0, wait (vmcnt(0) implicit in __syncthreads)
  STAGE(0, 0);
  __syncthreads();

  int cur = 0;
  for (int kt = 0; kt < nt; ++kt) {
    // issue next-tile loads BEFORE computing current (latency overlap)
    if (kt + 1 < nt) STAGE(cur ^ 1, (kt + 1) * 64);

    // compute current tile from LDS
#pragma unroll
    for (int kk = 0; kk < 2; ++kk) {
      bf16x8 a[4], bb[4];
      const int koff = kk * 32 + (l >> 4) * 8;
#pragma unroll
      for (int mi = 0; mi < 4; ++mi)
        a[mi] = *reinterpret_cast<const bf16x8*>(
            &As[cur][(wr * 64 + mi * 16 + (l & 15)) * 64 + koff]);
#pragma unroll
      for (int ni = 0; ni < 4; ++ni)
        bb[ni] = *reinterpret_cast<const bf16x8*>(
            &Bs[cur][(wc * 64 + ni * 16 + (l & 15)) * 64 + koff]);
      __builtin_amdgcn_s_setprio(1);
#pragma unroll
      for (int mi = 0; mi < 4; ++mi)
#pragma unroll
        for (int ni = 0; ni < 4; ++ni)
          acc[mi][ni] = __builtin_amdgcn_mfma_f32_16x16x32_bf16(
              a[mi], bb[ni], acc[mi][ni], 0, 0, 0);
      __builtin_amdgcn_s_setprio(0);
    }

    // single barrier per K-step; its implicit vmcnt(0) waits for the
    // prefetch issued at loop top (issued ~one compute-phase earlier)
    __syncthreads();
    cur ^= 1;
  }
#undef STAGE

  // ---- epilogue: C/D layout col=lane&15, row=(lane>>4)*4+reg ----
  if (EPI == 0) {
    __hip_bfloat16* out = (__hip_bfloat16*)outbase + (size_t)b * Mdim * Ndim;
#pragma unroll
    for (int mi = 0; mi < 4; ++mi) {
      const int row = r0 + wr * 64 + mi * 16 + (l >> 4) * 4;
#pragma unroll
      for (int ni = 0; ni < 4; ++ni) {
        const int col = n0 + wc * 64 + ni * 16 + (l & 15);
        const float bv = bias[col];
#pragma unroll
        for (int j = 0; j < 4; ++j) {
          float g = gelu_fast(acc[mi][ni][j] + bv);
          out[(size_t)(row + j) * Ndim + col] = __float2bfloat16(g);
        }
      }
    }
  } else {
    float* out = (float*)outbase + (size_t)b * Mdim * Ndim;
#pragma unroll
    for (int mi = 0; mi < 4; ++mi) {
      const int row = r0 + wr * 64 + mi * 16 + (l >> 4) * 4;
#pragma unroll
      for (int ni = 0; ni < 4; ++ni) {
        const int col = n0 + wc * 64 + ni * 16 + (l & 15);
        const float bv = bias[col];
#pragma unroll
        for (int j = 0; j < 4; ++j)
          out[(size_t)(row + j) * Ndim + col] = acc[mi][ni][j] + bv;
      }
    }
  }
}

// ---------------------------------------------------------------------------
extern "C" void kernel_launch(void* const* d_in, const int* in_sizes, int n_in,
                              void* d_out, int out_size, void* d_ws, size_t ws_size,
                              hipStream_t stream) {
  const float* x      = (const float*)d_in[0];
  const float* cond   = (const float*)d_in[1];
  const int*   route  = (const int*)d_in[2];    // harness passes integers as int32
  const float* W_cond = (const float*)d_in[3];
  const float* b_cond = (const float*)d_in[4];
  const float* W1     = (const float*)d_in[5];
  const float* b1     = (const float*)d_in[6];
  const float* W2     = (const float*)d_in[7];
  const float* b2     = (const float*)d_in[8];
  float* out = (float*)d_out;

  // workspace layout (bytes)
  const size_t SS_OFF   = 0;                                  // [B][1024] f32  = 32 KB
  const size_t XMOD_OFF = 32768;                              // [B][N][D] bf16 = 16 MB
  const size_t W1T_OFF  = XMOD_OFF + (size_t)BATCH * NTOK * DDIM * 2;       // [M][DFF][D] bf16
  const size_t W2T_OFF  = W1T_OFF + (size_t)NEXP * DDIM * DFFDIM * 2;       // [M][D][DFF] bf16
  const size_t H_OFF    = W2T_OFF + (size_t)NEXP * DFFDIM * DDIM * 2;       // [B][N][DFF] bf16
  const size_t NEED     = H_OFF + (size_t)BATCH * NTOK * DFFDIM * 2;
  if (ws_size < NEED) return;  // insufficient scratch -> visible failure

  char* ws = (char*)d_ws;
  float* ss            = (float*)(ws + SS_OFF);
  __hip_bfloat16* xmod = (__hip_bfloat16*)(ws + XMOD_OFF);
  __hip_bfloat16* w1t  = (__hip_bfloat16*)(ws + W1T_OFF);
  __hip_bfloat16* w2t  = (__hip_bfloat16*)(ws + W2T_OFF);
  __hip_bfloat16* h    = (__hip_bfloat16*)(ws + H_OFF);

  // 1) cond modulation
  mod_kernel<<<dim3(2 * DDIM / 256, BATCH), 256, 0, stream>>>(cond, route, W_cond, b_cond, ss);

  // 2) FiLM -> bf16
  {
    const size_t groups = (size_t)BATCH * NTOK * DDIM / 4;  // 2,097,152
    film_kernel<<<(unsigned)(groups / 256), 256, 0, stream>>>(x, ss, xmod);
  }

  // 3) weight transpose+convert (routed experts only):
  transpose_cvt<<<dim3(DFFDIM / 32, DDIM / 32, NEXP), dim3(32, 8), 0, stream>>>(W1, w1t, DDIM, DFFDIM, route);
  transpose_cvt<<<dim3(DDIM / 32, DFFDIM / 32, NEXP), dim3(32, 8), 0, stream>>>(W2, w2t, DFFDIM, DDIM, route);

  // 4) GEMM1: h = gelu(xmod @ W1 + b1)   grid 16*16*8 = 2048 blocks
  gemm_db<0><<<(NTOK / 128) * (DFFDIM / 128) * BATCH, 256, 0, stream>>>(
      xmod, w1t, b1, h, route, NTOK, DFFDIM, DDIM, NTOK / 128, DFFDIM / 128);

  // 5) GEMM2: out = h @ W2 + b2          grid 16*4*8 = 512 blocks
  gemm_db<1><<<(NTOK / 128) * (DDIM / 128) * BATCH, 256, 0, stream>>>(
      h, w2t, b2, out, route, NTOK, DDIM, DFFDIM, NTOK / 128, DDIM / 128);
}

// Round 4
// 146.155 us; speedup vs baseline: 1.4700x; 1.2819x over previous
//
#include <hip/hip_runtime.h>
#include <hip/hip_bf16.h>
#include <cstdint>
#include <cstddef>

// Problem dims (fixed by the reference)
#define NEXP   8
#define BATCH  8
#define NTOK   2048
#define DDIM   512
#define DFFDIM 2048
#define DCOND  512

typedef float  f32x4  __attribute__((ext_vector_type(4)));
typedef __bf16 bf16x8 __attribute__((ext_vector_type(8)));

using as1_cvoid = __attribute__((address_space(1))) const void;
using as3_void  = __attribute__((address_space(3))) void;

__device__ __forceinline__ void async_copy16(const void* g, void* l) {
  __builtin_amdgcn_global_load_lds((as1_cvoid*)g, (as3_void*)l, 16, 0, 0);
}

__device__ __forceinline__ unsigned short f2bf_bits(float f) {
  __hip_bfloat16 h = __float2bfloat16(f);
  return *reinterpret_cast<unsigned short*>(&h);
}

// fast tanh-approx gelu: 0.5v(1+tanh(z)) == v * sigmoid(2z)
__device__ __forceinline__ float gelu_fast(float v) {
  float y = v * fmaf(0.0713548162726f, v * v, 1.5957691216057f);
  float e = exp2f(-1.44269504089f * y);
  return v * __builtin_amdgcn_rcpf(1.0f + e);
}

// ---------------------------------------------------------------------------
// 1) scale/shift = cond[b] @ W_cond[route[b]] + b_cond[route[b]] -> ss[B][1024]
//    128 blocks: 64 j-columns each, c-dim split 4 ways + LDS reduce.
// ---------------------------------------------------------------------------
__global__ void mod_kernel(const float* __restrict__ cond,
                           const int* __restrict__ route,
                           const float* __restrict__ W_cond,
                           const float* __restrict__ b_cond,
                           float* __restrict__ ss) {
  const int b = blockIdx.y;
  const int m = route[b];
  const int tj = threadIdx.x & 63;
  const int cq = threadIdx.x >> 6;            // 0..3
  const int j = blockIdx.x * 64 + tj;
  const float* wc = W_cond + (size_t)m * DCOND * (2 * DDIM);
  const float* cb = cond + (size_t)b * DCOND;
  float acc = 0.f;
#pragma unroll 4
  for (int c = cq * 128; c < cq * 128 + 128; ++c)
    acc += cb[c] * wc[(size_t)c * (2 * DDIM) + j];
  __shared__ float red[4][64];
  red[cq][tj] = acc;
  __syncthreads();
  if (cq == 0) {
    float v = red[0][tj] + red[1][tj] + red[2][tj] + red[3][tj];
    ss[(size_t)b * (2 * DDIM) + j] = v + b_cond[(size_t)m * (2 * DDIM) + j];
  }
}

// ---------------------------------------------------------------------------
// 2) x_mod = bf16( x * (1+scale) + shift )   [B][N][D] bf16
// ---------------------------------------------------------------------------
__global__ void film_kernel(const float* __restrict__ x,
                            const float* __restrict__ ss,
                            __hip_bfloat16* __restrict__ xmod) {
  const size_t idx = (size_t)blockIdx.x * blockDim.x + threadIdx.x;
  const int d4 = (int)(idx & (DDIM / 4 - 1));
  const int b  = (int)(idx >> 18);
  const float4 xv = reinterpret_cast<const float4*>(x)[idx];
  const float4 sc = reinterpret_cast<const float4*>(ss + (size_t)b * 1024)[d4];
  const float4 sh = reinterpret_cast<const float4*>(ss + (size_t)b * 1024 + DDIM)[d4];
  float r0 = xv.x * (1.f + sc.x) + sh.x;
  float r1 = xv.y * (1.f + sc.y) + sh.y;
  float r2 = xv.z * (1.f + sc.z) + sh.z;
  float r3 = xv.w * (1.f + sc.w) + sh.w;
  ushort4 ov;
  ov.x = f2bf_bits(r0); ov.y = f2bf_bits(r1);
  ov.z = f2bf_bits(r2); ov.w = f2bf_bits(r3);
  reinterpret_cast<ushort4*>(xmod)[idx] = ov;
}

// ---------------------------------------------------------------------------
// 3) transpose + f32->bf16:  in [M][L][R] f32  ->  out [M][R][L] bf16
//    Skips experts not present in route.
// ---------------------------------------------------------------------------
__global__ void transpose_cvt(const float* __restrict__ in,
                              __hip_bfloat16* __restrict__ outp,
                              int L, int R,
                              const int* __restrict__ route) {
  const int mi = blockIdx.z;
  bool used = false;
#pragma unroll
  for (int b = 0; b < BATCH; ++b) used |= (route[b] == mi);
  if (!used) return;

  __shared__ float tile[32][33];
  const float* inm = in + (size_t)mi * L * R;
  __hip_bfloat16* outm = outp + (size_t)mi * L * R;
  const int r0 = blockIdx.x * 32, l0 = blockIdx.y * 32;
  const int tx = threadIdx.x, ty = threadIdx.y;
#pragma unroll
  for (int i = 0; i < 32; i += 8)
    tile[ty + i][tx] = inm[(size_t)(l0 + ty + i) * R + r0 + tx];
  __syncthreads();
#pragma unroll
  for (int i = 0; i < 32; i += 8)
    outm[(size_t)(r0 + ty + i) * L + l0 + tx] = __float2bfloat16(tile[tx][ty + i]);
}

// ---------------------------------------------------------------------------
// 4) Deep-pipelined GEMM: BM=256, BN=128, BK=64, 512 threads (8 waves 2Mx4N,
//    wave-tile 128x32).  A [b][Mdim][Kdim] bf16, Bt [m][Ndim][Kdim] bf16,
//    bias [m][Ndim] f32.  T2 XOR-swizzled LDS (linear gload_lds dest +
//    inverse-swizzled global src + swizzled ds_read).  Depth-2 tile prefetch
//    with counted vmcnt(6) (T4); raw s_barrier; setprio around MFMA (T5).
//    EPI=0: bf16(gelu(acc+bias));  EPI=1: f32(acc+bias).
//    Grid 1-D, batch = blockIdx&7 -> XCD-locality.
// ---------------------------------------------------------------------------
template <int EPI>
__global__ __launch_bounds__(512, 1) void gemm_pipe(
    const __hip_bfloat16* __restrict__ Abase,
    const __hip_bfloat16* __restrict__ Btbase,
    const float* __restrict__ biasbase,
    void* __restrict__ outbase,
    const int* __restrict__ route,
    int Mdim, int Ndim, int Kdim, int tilesX) {
  const int bid  = blockIdx.x;
  const int b    = bid & 7;            // batch -> XCD
  const int tile = bid >> 3;
  const int bx   = tile % tilesX;      // M-tile
  const int by   = tile / tilesX;      // N-tile
  const int m = route[b];
  const __hip_bfloat16* A  = Abase  + (size_t)b * Mdim * Kdim;
  const __hip_bfloat16* Bt = Btbase + (size_t)m * Ndim * Kdim;
  const float* bias = biasbase + (size_t)m * Ndim;
  const int r0 = bx * 256;
  const int n0 = by * 128;

  __shared__ alignas(16) __hip_bfloat16 As[2][256 * 64];   // 64 KB
  __shared__ alignas(16) __hip_bfloat16 Bs[2][128 * 64];   // 32 KB

  const int t = threadIdx.x;
  const int w = t >> 6, l = t & 63;
  const int wm = w >> 2, wn = w & 3;   // 2 x 4 waves

  // ---- staging source precompute (inverse-swizzled global chunk) ----
  // LDS 16B-chunk c_lin = i*512 + t  ->  LDS (row = i*64 + t>>3, chunk = t&7)
  // holds global chunk (t&7) ^ ((t>>3)&7) of the same row.
  const int srow = t >> 3;                     // 0..63
  const int scol = (t & 7) ^ ((t >> 3) & 7);   // 16B chunk in row, 0..7

#define STAGE_A(s, k0)                                                        \
  { _Pragma("unroll")                                                         \
    for (int i = 0; i < 4; ++i)                                               \
      async_copy16(A + (size_t)(r0 + i * 64 + srow) * Kdim + (k0) + scol * 8, \
                   &As[s][(i * 512 + w * 64) * 8]); }
#define STAGE_B(s, k0)                                                        \
  { _Pragma("unroll")                                                         \
    for (int i = 0; i < 2; ++i)                                               \
      async_copy16(Bt + (size_t)(n0 + i * 64 + srow) * Kdim + (k0) + scol * 8,\
                   &Bs[s][(i * 512 + w * 64) * 8]); }

  // ---- ds_read address precompute (swizzled) ----
  const int lrow = l & 15, lq = l >> 4, lx = l & 7;
  const int abase = (wm * 128 + lrow) * 8;     // 16B units
  const int bbase = (wn * 32 + lrow) * 8;
  const int swz0 = (lq) ^ lx;                  // kk=0 chunk
  const int swz1 = (4 + lq) ^ lx;              // kk=1 chunk

  f32x4 acc[8][2] = {};

  const int nt = Kdim >> 6;

  // prologue: stage tiles 0 and 1 (6 loads each)
  STAGE_A(0, 0) STAGE_B(0, 0)
  STAGE_A(1, 64) STAGE_B(1, 64)

  for (int kt = 0; kt < nt; ++kt) {
    const int s = kt & 1;
    // tile kt landed when <=6 loads (tile kt+1's) remain in flight
    if (kt + 1 < nt) asm volatile("s_waitcnt vmcnt(6)" ::: "memory");
    else             asm volatile("s_waitcnt vmcnt(0)" ::: "memory");
    __builtin_amdgcn_s_barrier();          // all waves' tile-kt data visible
    __builtin_amdgcn_sched_barrier(0);

    // read whole K-tile into registers (swizzled addresses)
    bf16x8 af[8][2], bfr[2][2];
#pragma unroll
    for (int mb = 0; mb < 8; ++mb) {
      af[mb][0] = *reinterpret_cast<const bf16x8*>(&As[s][(abase + mb * 128 + swz0) * 8]);
      af[mb][1] = *reinterpret_cast<const bf16x8*>(&As[s][(abase + mb * 128 + swz1) * 8]);
    }
#pragma unroll
    for (int nb = 0; nb < 2; ++nb) {
      bfr[nb][0] = *reinterpret_cast<const bf16x8*>(&Bs[s][(bbase + nb * 128 + swz0) * 8]);
      bfr[nb][1] = *reinterpret_cast<const bf16x8*>(&Bs[s][(bbase + nb * 128 + swz1) * 8]);
    }
    asm volatile("s_waitcnt lgkmcnt(0)" ::: "memory");
    __builtin_amdgcn_sched_barrier(0);
    __builtin_amdgcn_s_barrier();          // all waves done reading slot s
    __builtin_amdgcn_sched_barrier(0);

    // stage tile kt+2 into slot s (now free); lands ~2 groups later
    if (kt + 2 < nt) { STAGE_A(s, (kt + 2) * 64) STAGE_B(s, (kt + 2) * 64) }

    __builtin_amdgcn_s_setprio(1);
#pragma unroll
    for (int mb = 0; mb < 8; ++mb)
#pragma unroll
      for (int nb = 0; nb < 2; ++nb) {
        acc[mb][nb] = __builtin_amdgcn_mfma_f32_16x16x32_bf16(
            af[mb][0], bfr[nb][0], acc[mb][nb], 0, 0, 0);
        acc[mb][nb] = __builtin_amdgcn_mfma_f32_16x16x32_bf16(
            af[mb][1], bfr[nb][1], acc[mb][nb], 0, 0, 0);
      }
    __builtin_amdgcn_s_setprio(0);
  }
#undef STAGE_A
#undef STAGE_B

  // ---- epilogue: C/D layout col=lane&15, row=(lane>>4)*4+j ----
  if (EPI == 0) {
    __hip_bfloat16* out = (__hip_bfloat16*)outbase + (size_t)b * Mdim * Ndim;
#pragma unroll
    for (int mb = 0; mb < 8; ++mb) {
      const int row = r0 + wm * 128 + mb * 16 + lq * 4;
#pragma unroll
      for (int nb = 0; nb < 2; ++nb) {
        const int col = n0 + wn * 32 + nb * 16 + lrow;
        const float bv = bias[col];
#pragma unroll
        for (int j = 0; j < 4; ++j) {
          float g = gelu_fast(acc[mb][nb][j] + bv);
          out[(size_t)(row + j) * Ndim + col] = __float2bfloat16(g);
        }
      }
    }
  } else {
    float* out = (float*)outbase + (size_t)b * Mdim * Ndim;
#pragma unroll
    for (int mb = 0; mb < 8; ++mb) {
      const int row = r0 + wm * 128 + mb * 16 + lq * 4;
#pragma unroll
      for (int nb = 0; nb < 2; ++nb) {
        const int col = n0 + wn * 32 + nb * 16 + lrow;
        const float bv = bias[col];
#pragma unroll
        for (int j = 0; j < 4; ++j)
          out[(size_t)(row + j) * Ndim + col] = acc[mb][nb][j] + bv;
      }
    }
  }
}

// ---------------------------------------------------------------------------
extern "C" void kernel_launch(void* const* d_in, const int* in_sizes, int n_in,
                              void* d_out, int out_size, void* d_ws, size_t ws_size,
                              hipStream_t stream) {
  const float* x      = (const float*)d_in[0];
  const float* cond   = (const float*)d_in[1];
  const int*   route  = (const int*)d_in[2];
  const float* W_cond = (const float*)d_in[3];
  const float* b_cond = (const float*)d_in[4];
  const float* W1     = (const float*)d_in[5];
  const float* b1     = (const float*)d_in[6];
  const float* W2     = (const float*)d_in[7];
  const float* b2     = (const float*)d_in[8];
  float* out = (float*)d_out;

  // workspace layout (bytes)
  const size_t SS_OFF   = 0;
  const size_t XMOD_OFF = 32768;
  const size_t W1T_OFF  = XMOD_OFF + (size_t)BATCH * NTOK * DDIM * 2;
  const size_t W2T_OFF  = W1T_OFF + (size_t)NEXP * DDIM * DFFDIM * 2;
  const size_t H_OFF    = W2T_OFF + (size_t)NEXP * DFFDIM * DDIM * 2;
  const size_t NEED     = H_OFF + (size_t)BATCH * NTOK * DFFDIM * 2;
  if (ws_size < NEED) return;

  char* ws = (char*)d_ws;
  float* ss            = (float*)(ws + SS_OFF);
  __hip_bfloat16* xmod = (__hip_bfloat16*)(ws + XMOD_OFF);
  __hip_bfloat16* w1t  = (__hip_bfloat16*)(ws + W1T_OFF);
  __hip_bfloat16* w2t  = (__hip_bfloat16*)(ws + W2T_OFF);
  __hip_bfloat16* h    = (__hip_bfloat16*)(ws + H_OFF);

  // 1) cond modulation
  mod_kernel<<<dim3(2 * DDIM / 64, BATCH), 256, 0, stream>>>(cond, route, W_cond, b_cond, ss);

  // 2) FiLM -> bf16
  {
    const size_t groups = (size_t)BATCH * NTOK * DDIM / 4;
    film_kernel<<<(unsigned)(groups / 256), 256, 0, stream>>>(x, ss, xmod);
  }

  // 3) weight transpose+convert (routed experts only)
  transpose_cvt<<<dim3(DFFDIM / 32, DDIM / 32, NEXP), dim3(32, 8), 0, stream>>>(W1, w1t, DDIM, DFFDIM, route);
  transpose_cvt<<<dim3(DDIM / 32, DFFDIM / 32, NEXP), dim3(32, 8), 0, stream>>>(W2, w2t, DFFDIM, DDIM, route);

  // 4) GEMM1: h = gelu(xmod @ W1 + b1)   grid (2048/256)*(2048/128)*8 = 1024
  gemm_pipe<0><<<(NTOK / 256) * (DFFDIM / 128) * BATCH, 512, 0, stream>>>(
      xmod, w1t, b1, h, route, NTOK, DFFDIM, DDIM, NTOK / 256);

  // 5) GEMM2: out = h @ W2 + b2          grid (2048/256)*(512/128)*8 = 256
  gemm_pipe<1><<<(NTOK / 256) * (DDIM / 128) * BATCH, 512, 0, stream>>>(
      h, w2t, b2, out, route, NTOK, DDIM, DFFDIM, NTOK / 256);
}